// Round 15
// baseline (183.145 us; speedup 1.0000x reference)
//
#include <hip/hip_runtime.h>
#include <math.h>

typedef float  f32x4  __attribute__((ext_vector_type(4)));
typedef int    i32x4  __attribute__((ext_vector_type(4)));

#define H      4096
#define E      64
#define TOPK   8
#define TILE_T 32
#define CK     256     // k per staged chunk
#define MS     4       // 64-k MFMA steps per chunk
#define NCH    16      // chunks

// W -> 5 balanced i8 limbs of round(w*2^41), B-fragment order for 16x16x64
// (R11-proven): Wb[((m*4+eq)*5+j)*1024 + lane*16 + slot], lane=(kgrp<<4)|(e&15)
__global__ __launch_bounds__(256)
void prep_w(const float* __restrict__ Wg, signed char* __restrict__ Wb)
{
  int n = blockIdx.x * 256 + threadIdx.x;   // 16384 = e(64) x m(64) x kgrp(4)
  int kgrp = n & 3, m = (n >> 2) & 63, e = n >> 8;
  const float* wp = Wg + e * 4096 + m * 64 + kgrp * 16;
  signed char lb[5][16];
  #pragma unroll
  for (int s = 0; s < 16; ++s) {
    long long v = (long long)rint((double)wp[s] * 2199023255552.0); // 2^41
    #pragma unroll
    for (int j = 0; j < 4; ++j) {
      signed char b = (signed char)(v & 0xff);
      lb[j][s] = b;
      v = (v - b) >> 8;
    }
    lb[4][s] = (signed char)v;
  }
  int lanei = (kgrp << 4) | (e & 15);
  int eq = e >> 4;
  #pragma unroll
  for (int j = 0; j < 5; ++j) {
    i32x4 d;
    #pragma unroll
    for (int r = 0; r < 4; ++r)
      d[r] = (lb[j][4*r] & 0xFF) | ((lb[j][4*r+1] & 0xFF) << 8)
           | ((lb[j][4*r+2] & 0xFF) << 16) | ((lb[j][4*r+3] & 0xFF) << 24);
    *(i32x4*)(Wb + (((size_t)(m * 4 + eq) * 5 + j) << 10) + lanei * 16) = d;
  }
}

// comp[e] = C0 * sum_k round(w*2^41), full K (R11-proven).
__global__ __launch_bounds__(64)
void comp_w(const float* __restrict__ Wg, double* __restrict__ compT)
{
  int e = blockIdx.x;
  int lane = threadIdx.x;
  double s = 0.0;
  #pragma unroll 4
  for (int i = 0; i < 64; ++i)
    s += rint((double)Wg[e * 4096 + i * 64 + lane] * 2199023255552.0);
  #pragma unroll
  for (int off = 32; off >= 1; off >>= 1)
    s += __shfl_xor(s, off);
  if (lane == 0) compT[e] = 8421504.0 * s;
}

// R15: within-wave pipeline. Per iteration (single straight-line region):
// {issue next-chunk loads} -> {consume current chunk: 112 MFMAs} ->
// {convert next chunk, reg-only VALU in the MFMA shadow} -> barrier ->
// {LDS write} -> barrier. R14 serialized these phases; MFMA sat idle
// during convert and vice versa. launch_bounds(256,2): grid=512 caps us
// at 2 blocks/CU anyway, so lift the VGPR cap for scheduling freedom.
__global__ __launch_bounds__(256, 2)
void moe_gate_i8(const float* __restrict__ X, const signed char* __restrict__ Wb,
                 const double* __restrict__ compT, float* __restrict__ out,
                 int n_tokens)
{
  __shared__ char sm[32768];       // As: [kgrp 16][limb 4][tok 32]x16B swizzled
  double* Ls = (double*)sm;        // [32][64] f64 logits, aliased after loop

  const int tid  = threadIdx.x;
  const int lane = tid & 63;
  const int w    = tid >> 6;     // expert quad 0..3
  const int t0   = blockIdx.x * TILE_T;
  const int l15  = lane & 15;
  const int kg   = lane >> 4;

  // ---- probe (lane,reg)->(row,col) readout (R11-proven) ----
  i32x4 z = {0, 0, 0, 0};
  int lab = l15 * 0x01010101;
  i32x4 onev = {0x01010101, 0x01010101, 0x01010101, 0x01010101};
  i32x4 labv = {lab, lab, lab, lab};
  i32x4 pr = __builtin_amdgcn_mfma_i32_16x16x64_i8(labv, onev, z, 0, 0, 0);
  i32x4 pc = __builtin_amdgcn_mfma_i32_16x16x64_i8(onev, labv, z, 0, 0, 0);
  int qrow[4], qcol[4];
  #pragma unroll
  for (int r = 0; r < 4; ++r) { qrow[r] = pr[r] >> 6; qcol[r] = pc[r] >> 6; }

  // two token-tiles x five scale-classes
  i32x4 aA3 = z, aA4 = z, aA5 = z, aA6 = z, aA7 = z;
  i32x4 aB3 = z, aB4 = z, aB5 = z, aB6 = z, aB7 = z;

  // staging: thread = (token tt 0..31, 32-float segment ks 0..7)
  const int tt = tid >> 3;
  const int ks = tid & 7;
  const int kgrpw = ks * 2;                    // write kgrp base
  const int swzw  = ks << 4;                   // ((kgrp>>1)&7)<<4
  char* wbase0 = sm + ((kgrpw + 0) << 11) + (((tt << 4) ^ swzw));
  char* wbase1 = sm + ((kgrpw + 1) << 11) + (((tt << 4) ^ swzw));
  const float* xp = X + (size_t)(t0 + tt) * H + ks * 32;

  const signed char* bpp = Wb + w * 5120 + lane * 16;

  // convert xr -> one kgrp's 4 limb-plane words (R9-verified perm tree)
  #define CONV(xr, hf, W0, W1, W2, W3)                                        \
  {                                                                           \
    unsigned w32[16];                                                         \
    _Pragma("unroll")                                                         \
    for (int r = 0; r < 4; ++r) {                                             \
      f32x4 xv = xr[(hf) * 4 + r];                                            \
      _Pragma("unroll")                                                       \
      for (int jj = 0; jj < 4; ++jj)                                          \
        w32[r*4+jj] = ((unsigned)(int)(xv[jj] * 268435456.0f)) ^ 0x00808080u; \
    }                                                                         \
    _Pragma("unroll")                                                         \
    for (int r = 0; r < 4; ++r) {                                             \
      unsigned u0 = w32[4*r], u1 = w32[4*r+1], u2 = w32[4*r+2], u3 = w32[4*r+3];\
      unsigned p01, p23;                                                      \
      p01 = __builtin_amdgcn_perm(u1, u0, 0x04000400u);                       \
      p23 = __builtin_amdgcn_perm(u3, u2, 0x04000400u);                       \
      W0[r] = (int)__builtin_amdgcn_perm(p23, p01, 0x05040100u);              \
      p01 = __builtin_amdgcn_perm(u1, u0, 0x05010501u);                       \
      p23 = __builtin_amdgcn_perm(u3, u2, 0x05010501u);                       \
      W1[r] = (int)__builtin_amdgcn_perm(p23, p01, 0x05040100u);              \
      p01 = __builtin_amdgcn_perm(u1, u0, 0x06020602u);                       \
      p23 = __builtin_amdgcn_perm(u3, u2, 0x06020602u);                       \
      W2[r] = (int)__builtin_amdgcn_perm(p23, p01, 0x05040100u);              \
      p01 = __builtin_amdgcn_perm(u1, u0, 0x07030703u);                       \
      p23 = __builtin_amdgcn_perm(u3, u2, 0x07030703u);                       \
      W3[r] = (int)__builtin_amdgcn_perm(p23, p01, 0x05040100u);              \
    }                                                                         \
  }

  // ---- prologue: chunk 0 ----
  {
    f32x4 xr[8];
    #pragma unroll
    for (int q = 0; q < 8; ++q) xr[q] = *(const f32x4*)(xp + 4 * q);
    xp += CK;
    i32x4 U0, U1, U2, U3, V0, V1, V2, V3;
    CONV(xr, 0, U0, U1, U2, U3);
    CONV(xr, 1, V0, V1, V2, V3);
    *(i32x4*)(wbase0 + 0x000) = U0;
    *(i32x4*)(wbase0 + 0x200) = U1;
    *(i32x4*)(wbase0 + 0x400) = U2;
    *(i32x4*)(wbase0 + 0x600) = U3;
    *(i32x4*)(wbase1 + 0x000) = V0;
    *(i32x4*)(wbase1 + 0x200) = V1;
    *(i32x4*)(wbase1 + 0x400) = V2;
    *(i32x4*)(wbase1 + 0x600) = V3;
  }
  __syncthreads();

  for (int c = 0; c < NCH; ++c) {
    // 1) issue next-chunk loads (last iter: re-reads chunk 15, unused)
    f32x4 xr[8];
    #pragma unroll
    for (int q = 0; q < 8; ++q) xr[q] = *(const f32x4*)(xp + 4 * q);
    xp += (c < NCH - 2) ? CK : 0;

    // 2) consume current chunk: MS x {5 B loads + 8 ds_read + 28 MFMAs}
    #pragma unroll
    for (int m = 0; m < MS; ++m) {
      const int kq   = 4 * m + kg;
      const int swzr = ((kq >> 1) & 7) << 4;
      const char* abase = sm + (kq << 11) + (((l15 << 4) ^ swzr));
      i32x4 b0 = *(const i32x4*)(bpp);
      i32x4 b1 = *(const i32x4*)(bpp + 1024);
      i32x4 b2 = *(const i32x4*)(bpp + 2048);
      i32x4 b3 = *(const i32x4*)(bpp + 3072);
      i32x4 b4 = *(const i32x4*)(bpp + 4096);
      bpp += 20480;
      i32x4 xA0 = *(const i32x4*)(abase + 0x000);
      i32x4 xA1 = *(const i32x4*)(abase + 0x200);
      i32x4 xA2 = *(const i32x4*)(abase + 0x400);
      i32x4 xA3 = *(const i32x4*)(abase + 0x600);
      i32x4 xB0 = *(const i32x4*)(abase + 0x100);
      i32x4 xB1 = *(const i32x4*)(abase + 0x300);
      i32x4 xB2 = *(const i32x4*)(abase + 0x500);
      i32x4 xB3 = *(const i32x4*)(abase + 0x700);
      aA3 = __builtin_amdgcn_mfma_i32_16x16x64_i8(xA0, b3, aA3, 0, 0, 0);
      aB3 = __builtin_amdgcn_mfma_i32_16x16x64_i8(xB0, b3, aB3, 0, 0, 0);
      aA4 = __builtin_amdgcn_mfma_i32_16x16x64_i8(xA0, b4, aA4, 0, 0, 0);
      aB4 = __builtin_amdgcn_mfma_i32_16x16x64_i8(xB0, b4, aB4, 0, 0, 0);
      aA5 = __builtin_amdgcn_mfma_i32_16x16x64_i8(xA1, b4, aA5, 0, 0, 0);
      aB5 = __builtin_amdgcn_mfma_i32_16x16x64_i8(xB1, b4, aB5, 0, 0, 0);
      aA6 = __builtin_amdgcn_mfma_i32_16x16x64_i8(xA2, b4, aA6, 0, 0, 0);
      aB6 = __builtin_amdgcn_mfma_i32_16x16x64_i8(xB2, b4, aB6, 0, 0, 0);
      aA7 = __builtin_amdgcn_mfma_i32_16x16x64_i8(xA3, b4, aA7, 0, 0, 0);
      aB7 = __builtin_amdgcn_mfma_i32_16x16x64_i8(xB3, b4, aB7, 0, 0, 0);
      aA3 = __builtin_amdgcn_mfma_i32_16x16x64_i8(xA1, b2, aA3, 0, 0, 0);
      aB3 = __builtin_amdgcn_mfma_i32_16x16x64_i8(xB1, b2, aB3, 0, 0, 0);
      aA4 = __builtin_amdgcn_mfma_i32_16x16x64_i8(xA1, b3, aA4, 0, 0, 0);
      aB4 = __builtin_amdgcn_mfma_i32_16x16x64_i8(xB1, b3, aB4, 0, 0, 0);
      aA5 = __builtin_amdgcn_mfma_i32_16x16x64_i8(xA2, b3, aA5, 0, 0, 0);
      aB5 = __builtin_amdgcn_mfma_i32_16x16x64_i8(xB2, b3, aB5, 0, 0, 0);
      aA6 = __builtin_amdgcn_mfma_i32_16x16x64_i8(xA3, b3, aA6, 0, 0, 0);
      aB6 = __builtin_amdgcn_mfma_i32_16x16x64_i8(xB3, b3, aB6, 0, 0, 0);
      aA3 = __builtin_amdgcn_mfma_i32_16x16x64_i8(xA2, b1, aA3, 0, 0, 0);
      aB3 = __builtin_amdgcn_mfma_i32_16x16x64_i8(xB2, b1, aB3, 0, 0, 0);
      aA4 = __builtin_amdgcn_mfma_i32_16x16x64_i8(xA2, b2, aA4, 0, 0, 0);
      aB4 = __builtin_amdgcn_mfma_i32_16x16x64_i8(xB2, b2, aB4, 0, 0, 0);
      aA5 = __builtin_amdgcn_mfma_i32_16x16x64_i8(xA3, b2, aA5, 0, 0, 0);
      aB5 = __builtin_amdgcn_mfma_i32_16x16x64_i8(xB3, b2, aB5, 0, 0, 0);
      aA3 = __builtin_amdgcn_mfma_i32_16x16x64_i8(xA3, b0, aA3, 0, 0, 0);
      aB3 = __builtin_amdgcn_mfma_i32_16x16x64_i8(xB3, b0, aB3, 0, 0, 0);
      aA4 = __builtin_amdgcn_mfma_i32_16x16x64_i8(xA3, b1, aA4, 0, 0, 0);
      aB4 = __builtin_amdgcn_mfma_i32_16x16x64_i8(xB3, b1, aB4, 0, 0, 0);
    }

    // 3) convert next chunk in registers (VALU, overlaps MFMA shadow)
    i32x4 U0, U1, U2, U3, V0, V1, V2, V3;
    CONV(xr, 0, U0, U1, U2, U3);
    CONV(xr, 1, V0, V1, V2, V3);

    // 4) all waves done reading As -> overwrite
    __syncthreads();
    *(i32x4*)(wbase0 + 0x000) = U0;
    *(i32x4*)(wbase0 + 0x200) = U1;
    *(i32x4*)(wbase0 + 0x400) = U2;
    *(i32x4*)(wbase0 + 0x600) = U3;
    *(i32x4*)(wbase1 + 0x000) = V0;
    *(i32x4*)(wbase1 + 0x200) = V1;
    *(i32x4*)(wbase1 + 0x400) = V2;
    *(i32x4*)(wbase1 + 0x600) = V3;
    __syncthreads();
  }
  #undef CONV

  // ---- f64 combine (As is dead; Ls aliases it) ----
  #pragma unroll
  for (int r = 0; r < 4; ++r) {
    int ex = w * 16 + qcol[r];
    double pA = (16777216.0          * (double)aA3[r]
               + 4294967296.0        * (double)aA4[r]
               + 1099511627776.0     * (double)aA5[r]
               + 281474976710656.0   * (double)aA6[r]
               + 72057594037927936.0 * (double)aA7[r]
               + compT[ex]) * 1.6940658945086007e-21;
    double pB = (16777216.0          * (double)aB3[r]
               + 4294967296.0        * (double)aB4[r]
               + 1099511627776.0     * (double)aB5[r]
               + 281474976710656.0   * (double)aB6[r]
               + 72057594037927936.0 * (double)aB7[r]
               + compT[ex]) * 1.6940658945086007e-21;
    Ls[qrow[r] * E + ex]        = pA;
    Ls[(16 + qrow[r]) * E + ex] = pB;
  }
  __syncthreads();

  // ---- softmax + top-8: selection on f64 logits, weights in f32 ----
  for (int tt2 = 0; tt2 < 8; tt2++) {
    int t = w * 8 + tt2;
    double val = Ls[t * E + lane];

    double mx = val;
    #pragma unroll
    for (int off = 32; off >= 1; off >>= 1)
      mx = fmax(mx, __shfl_xor(mx, off));

    float p = expf((float)(val - mx));
    float S = p;
    #pragma unroll
    for (int off = 32; off >= 1; off >>= 1)
      S += __shfl_xor(S, off);

    double cur = val;
    float myw = 0.f; int myidx = 0;
    float psum = 0.f;
    #pragma unroll
    for (int r = 0; r < TOPK; r++) {
      double v = cur; int ii = lane;
      #pragma unroll
      for (int off = 32; off >= 1; off >>= 1) {
        double ov = __shfl_xor(v, off);
        int    oi = __shfl_xor(ii, off);
        if (ov > v || (ov == v && oi < ii)) { v = ov; ii = oi; }
      }
      float pw = __shfl(p, ii);
      psum += pw;
      if (lane == r) { myw = pw; myidx = ii; }
      if (lane == ii) cur = -INFINITY;
    }
    float denom = psum + 1e-20f * S;
    if (lane < TOPK) {
      size_t gt = (size_t)(t0 + t);
      out[gt * TOPK + lane] = myw / denom;
      out[(size_t)n_tokens * TOPK + gt * TOPK + lane] = (float)myidx;
    }
  }
}

extern "C" void kernel_launch(void* const* d_in, const int* in_sizes, int n_in,
                              void* d_out, int out_size, void* d_ws, size_t ws_size,
                              hipStream_t stream)
{
  const float* X  = (const float*)d_in[0];
  const float* Wg = (const float*)d_in[1];
  float* out = (float*)d_out;
  signed char* Wb = (signed char*)d_ws;                 // 1.25 MB limb planes
  double* compT   = (double*)((char*)d_ws + 1310720);   // 512 B comp table
  int n_tokens = in_sizes[0] / H;                        // 16384

  prep_w<<<64, 256, 0, stream>>>(Wg, Wb);
  comp_w<<<64, 64, 0, stream>>>(Wg, compT);
  moe_gate_i8<<<n_tokens / TILE_T, 256, 0, stream>>>(X, Wb, compT, out, n_tokens);
}

// Round 16
// 144.927 us; speedup vs baseline: 1.2637x; 1.2637x over previous
//
#include <hip/hip_runtime.h>
#include <math.h>

typedef float  f32x4  __attribute__((ext_vector_type(4)));
typedef int    i32x4  __attribute__((ext_vector_type(4)));

#define H      4096
#define E      64
#define TOPK   8
#define TILE_T 32
#define CK     256     // k per staged chunk
#define MS     4       // 64-k MFMA steps per chunk
#define NCH    16      // chunks

// W -> 5 balanced i8 limbs of round(w*2^41), B-fragment order for 16x16x64
// (R11-proven): Wb[((m*4+eq)*5+j)*1024 + lane*16 + slot], lane=(kgrp<<4)|(e&15)
__global__ __launch_bounds__(256)
void prep_w(const float* __restrict__ Wg, signed char* __restrict__ Wb)
{
  int n = blockIdx.x * 256 + threadIdx.x;   // 16384 = e(64) x m(64) x kgrp(4)
  int kgrp = n & 3, m = (n >> 2) & 63, e = n >> 8;
  const float* wp = Wg + e * 4096 + m * 64 + kgrp * 16;
  signed char lb[5][16];
  #pragma unroll
  for (int s = 0; s < 16; ++s) {
    long long v = (long long)rint((double)wp[s] * 2199023255552.0); // 2^41
    #pragma unroll
    for (int j = 0; j < 4; ++j) {
      signed char b = (signed char)(v & 0xff);
      lb[j][s] = b;
      v = (v - b) >> 8;
    }
    lb[4][s] = (signed char)v;
  }
  int lanei = (kgrp << 4) | (e & 15);
  int eq = e >> 4;
  #pragma unroll
  for (int j = 0; j < 5; ++j) {
    i32x4 d;
    #pragma unroll
    for (int r = 0; r < 4; ++r)
      d[r] = (lb[j][4*r] & 0xFF) | ((lb[j][4*r+1] & 0xFF) << 8)
           | ((lb[j][4*r+2] & 0xFF) << 16) | ((lb[j][4*r+3] & 0xFF) << 24);
    *(i32x4*)(Wb + (((size_t)(m * 4 + eq) * 5 + j) << 10) + lanei * 16) = d;
  }
}

// comp[e] = C0 * sum_k round(w*2^41), full K (R11-proven).
__global__ __launch_bounds__(64)
void comp_w(const float* __restrict__ Wg, double* __restrict__ compT)
{
  int e = blockIdx.x;
  int lane = threadIdx.x;
  double s = 0.0;
  #pragma unroll 4
  for (int i = 0; i < 64; ++i)
    s += rint((double)Wg[e * 4096 + i * 64 + lane] * 2199023255552.0);
  #pragma unroll
  for (int off = 32; off >= 1; off >>= 1)
    s += __shfl_xor(s, off);
  if (lane == 0) compT[e] = 8421504.0 * s;
}

// R16: m97-shape loop. Raw f32 X staged via global_load_lds (async,
// double-buffered, source-side XOR swizzle); conversion moved to the
// CONSUMER side (ds_read -> CONV in regs -> MFMA; lgkmcnt path, independent
// of vmcnt). Per chunk, ALL 20 B loads are hoisted BEFORE the stage issues
// so the compiler's B-wait is a counted vmcnt that leaves stage loads in
// flight (R15's bug: stage issued first -> in-order vmcnt drained HBM every
// chunk). Numerics byte-identical to R8-R15.
__global__ __launch_bounds__(256)
void moe_gate_i8(const float* __restrict__ X, const signed char* __restrict__ Wb,
                 const double* __restrict__ compT, float* __restrict__ out,
                 int n_tokens)
{
  __shared__ char sm[65536];       // 2 x 32KB raw-f32 X buffers [tok32][k256]
  double* Ls = (double*)sm;        // aliased epilogue logits [32][64]

  const int tid  = threadIdx.x;
  const int lane = tid & 63;
  const int w    = tid >> 6;     // expert quad 0..3
  const int t0   = blockIdx.x * TILE_T;
  const int l15  = lane & 15;
  const int kg   = lane >> 4;
  const int dA   = l15 & 7;      // read-side swizzle key (token row)

  // ---- probe (lane,reg)->(row,col) readout (R11-proven) ----
  i32x4 z = {0, 0, 0, 0};
  int lab = l15 * 0x01010101;
  i32x4 onev = {0x01010101, 0x01010101, 0x01010101, 0x01010101};
  i32x4 labv = {lab, lab, lab, lab};
  i32x4 pr = __builtin_amdgcn_mfma_i32_16x16x64_i8(labv, onev, z, 0, 0, 0);
  i32x4 pc = __builtin_amdgcn_mfma_i32_16x16x64_i8(onev, labv, z, 0, 0, 0);
  int qrow[4], qcol[4];
  #pragma unroll
  for (int r = 0; r < 4; ++r) { qrow[r] = pr[r] >> 6; qcol[r] = pc[r] >> 6; }

  // two token-tiles x five scale-classes
  i32x4 aA3 = z, aA4 = z, aA5 = z, aA6 = z, aA7 = z;
  i32x4 aB3 = z, aB4 = z, aB5 = z, aB6 = z, aB7 = z;

  const signed char* bpp = Wb + w * 5120 + lane * 16;

  // stage one chunk: wave w stages rows w*8..w*8+7; lane fetches global
  // granule (lane ^ (tok&7)) so LDS slot s holds granule (s ^ (tok&7))
  #define STAGE(c_, buf_)                                                     \
  {                                                                           \
    _Pragma("unroll")                                                         \
    for (int q = 0; q < 8; ++q) {                                             \
      const int tok_ = w * 8 + q;                                             \
      const float* src_ = X + (size_t)(t0 + tok_) * H + (c_) * CK             \
                            + ((lane ^ (tok_ & 7)) << 2);                     \
      char* dst_ = sm + ((buf_) << 15) + (tok_ << 10);                        \
      __builtin_amdgcn_global_load_lds(                                       \
          (const __attribute__((address_space(1))) void*)src_,                \
          (__attribute__((address_space(3))) void*)dst_, 16, 0, 0);           \
    }                                                                         \
  }

  // convert 4 x f32x4 (16 k-slots) -> 4 limb-plane words (R9-proven tree)
  #define CONV4(xv, W0, W1, W2, W3)                                           \
  {                                                                           \
    unsigned w32[16];                                                         \
    _Pragma("unroll")                                                         \
    for (int r = 0; r < 4; ++r) {                                             \
      f32x4 t_ = xv[r];                                                       \
      _Pragma("unroll")                                                       \
      for (int jj = 0; jj < 4; ++jj)                                          \
        w32[r*4+jj] = ((unsigned)(int)(t_[jj] * 268435456.0f)) ^ 0x00808080u; \
    }                                                                         \
    _Pragma("unroll")                                                         \
    for (int r = 0; r < 4; ++r) {                                             \
      unsigned u0 = w32[4*r], u1 = w32[4*r+1], u2 = w32[4*r+2], u3 = w32[4*r+3];\
      unsigned p01, p23;                                                      \
      p01 = __builtin_amdgcn_perm(u1, u0, 0x04000400u);                       \
      p23 = __builtin_amdgcn_perm(u3, u2, 0x04000400u);                       \
      W0[r] = (int)__builtin_amdgcn_perm(p23, p01, 0x05040100u);              \
      p01 = __builtin_amdgcn_perm(u1, u0, 0x05010501u);                       \
      p23 = __builtin_amdgcn_perm(u3, u2, 0x05010501u);                       \
      W1[r] = (int)__builtin_amdgcn_perm(p23, p01, 0x05040100u);              \
      p01 = __builtin_amdgcn_perm(u1, u0, 0x06020602u);                       \
      p23 = __builtin_amdgcn_perm(u3, u2, 0x06020602u);                       \
      W2[r] = (int)__builtin_amdgcn_perm(p23, p01, 0x05040100u);              \
      p01 = __builtin_amdgcn_perm(u1, u0, 0x07030703u);                       \
      p23 = __builtin_amdgcn_perm(u3, u2, 0x07030703u);                       \
      W3[r] = (int)__builtin_amdgcn_perm(p23, p01, 0x05040100u);              \
    }                                                                         \
  }

  // ---- prologue: stage chunk 0 into buf 0 ----
  STAGE(0, 0);
  __syncthreads();   // vmcnt(0) drain + barrier: buf0 ready

  for (int c = 0; c < NCH; ++c) {
    const int cur = c & 1;

    // 1) hoist ALL of this chunk's B loads (L2) BEFORE the stage issues
    i32x4 bf[4][5];
    #pragma unroll
    for (int m = 0; m < MS; ++m)
      #pragma unroll
      for (int j = 0; j < 5; ++j)
        bf[m][j] = *(const i32x4*)(bpp + (size_t)m * 20480 + (j << 10));
    bpp += (size_t)MS * 20480;

    // 2) issue next-chunk stage (stays in flight through consume)
    if (c < NCH - 1) STAGE(c + 1, cur ^ 1);

    // 3) consume current buffer: MS x {8 ds_read + CONV + 28 MFMAs}
    const char* base = sm + (cur << 15);
    #pragma unroll
    for (int m = 0; m < MS; ++m) {
      f32x4 va[4], vb[4];
      #pragma unroll
      for (int j = 0; j < 4; ++j) {
        const int slot = ((m * 16 + kg * 4 + j) ^ dA) << 4;
        va[j] = *(const f32x4*)(base + (l15 << 10) + slot);
        vb[j] = *(const f32x4*)(base + ((l15 + 16) << 10) + slot);
      }
      i32x4 xA0, xA1, xA2, xA3, xB0, xB1, xB2, xB3;
      CONV4(va, xA0, xA1, xA2, xA3);
      CONV4(vb, xB0, xB1, xB2, xB3);
      i32x4 b0 = bf[m][0], b1 = bf[m][1], b2 = bf[m][2], b3 = bf[m][3], b4 = bf[m][4];
      aA3 = __builtin_amdgcn_mfma_i32_16x16x64_i8(xA0, b3, aA3, 0, 0, 0);
      aB3 = __builtin_amdgcn_mfma_i32_16x16x64_i8(xB0, b3, aB3, 0, 0, 0);
      aA4 = __builtin_amdgcn_mfma_i32_16x16x64_i8(xA0, b4, aA4, 0, 0, 0);
      aB4 = __builtin_amdgcn_mfma_i32_16x16x64_i8(xB0, b4, aB4, 0, 0, 0);
      aA5 = __builtin_amdgcn_mfma_i32_16x16x64_i8(xA1, b4, aA5, 0, 0, 0);
      aB5 = __builtin_amdgcn_mfma_i32_16x16x64_i8(xB1, b4, aB5, 0, 0, 0);
      aA6 = __builtin_amdgcn_mfma_i32_16x16x64_i8(xA2, b4, aA6, 0, 0, 0);
      aB6 = __builtin_amdgcn_mfma_i32_16x16x64_i8(xB2, b4, aB6, 0, 0, 0);
      aA7 = __builtin_amdgcn_mfma_i32_16x16x64_i8(xA3, b4, aA7, 0, 0, 0);
      aB7 = __builtin_amdgcn_mfma_i32_16x16x64_i8(xB3, b4, aB7, 0, 0, 0);
      aA3 = __builtin_amdgcn_mfma_i32_16x16x64_i8(xA1, b2, aA3, 0, 0, 0);
      aB3 = __builtin_amdgcn_mfma_i32_16x16x64_i8(xB1, b2, aB3, 0, 0, 0);
      aA4 = __builtin_amdgcn_mfma_i32_16x16x64_i8(xA1, b3, aA4, 0, 0, 0);
      aB4 = __builtin_amdgcn_mfma_i32_16x16x64_i8(xB1, b3, aB4, 0, 0, 0);
      aA5 = __builtin_amdgcn_mfma_i32_16x16x64_i8(xA2, b3, aA5, 0, 0, 0);
      aB5 = __builtin_amdgcn_mfma_i32_16x16x64_i8(xB2, b3, aB5, 0, 0, 0);
      aA6 = __builtin_amdgcn_mfma_i32_16x16x64_i8(xA3, b3, aA6, 0, 0, 0);
      aB6 = __builtin_amdgcn_mfma_i32_16x16x64_i8(xB3, b3, aB6, 0, 0, 0);
      aA3 = __builtin_amdgcn_mfma_i32_16x16x64_i8(xA2, b1, aA3, 0, 0, 0);
      aB3 = __builtin_amdgcn_mfma_i32_16x16x64_i8(xB2, b1, aB3, 0, 0, 0);
      aA4 = __builtin_amdgcn_mfma_i32_16x16x64_i8(xA2, b2, aA4, 0, 0, 0);
      aB4 = __builtin_amdgcn_mfma_i32_16x16x64_i8(xB2, b2, aB4, 0, 0, 0);
      aA5 = __builtin_amdgcn_mfma_i32_16x16x64_i8(xA3, b2, aA5, 0, 0, 0);
      aB5 = __builtin_amdgcn_mfma_i32_16x16x64_i8(xB3, b2, aB5, 0, 0, 0);
      aA3 = __builtin_amdgcn_mfma_i32_16x16x64_i8(xA3, b0, aA3, 0, 0, 0);
      aB3 = __builtin_amdgcn_mfma_i32_16x16x64_i8(xB3, b0, aB3, 0, 0, 0);
      aA4 = __builtin_amdgcn_mfma_i32_16x16x64_i8(xA3, b1, aA4, 0, 0, 0);
      aB4 = __builtin_amdgcn_mfma_i32_16x16x64_i8(xB3, b1, aB4, 0, 0, 0);
    }

    // 4) chunk boundary: readers done + staged chunk c+1 landed
    __syncthreads();
  }
  #undef STAGE
  #undef CONV4

  // ---- f64 combine (staging dead; Ls aliases it) ----
  #pragma unroll
  for (int r = 0; r < 4; ++r) {
    int ex = w * 16 + qcol[r];
    double pA = (16777216.0          * (double)aA3[r]
               + 4294967296.0        * (double)aA4[r]
               + 1099511627776.0     * (double)aA5[r]
               + 281474976710656.0   * (double)aA6[r]
               + 72057594037927936.0 * (double)aA7[r]
               + compT[ex]) * 1.6940658945086007e-21;
    double pB = (16777216.0          * (double)aB3[r]
               + 4294967296.0        * (double)aB4[r]
               + 1099511627776.0     * (double)aB5[r]
               + 281474976710656.0   * (double)aB6[r]
               + 72057594037927936.0 * (double)aB7[r]
               + compT[ex]) * 1.6940658945086007e-21;
    Ls[qrow[r] * E + ex]        = pA;
    Ls[(16 + qrow[r]) * E + ex] = pB;
  }
  __syncthreads();

  // ---- softmax + top-8: selection on f64 logits, weights in f32 ----
  for (int tt2 = 0; tt2 < 8; tt2++) {
    int t = w * 8 + tt2;
    double val = Ls[t * E + lane];

    double mx = val;
    #pragma unroll
    for (int off = 32; off >= 1; off >>= 1)
      mx = fmax(mx, __shfl_xor(mx, off));

    float p = expf((float)(val - mx));
    float S = p;
    #pragma unroll
    for (int off = 32; off >= 1; off >>= 1)
      S += __shfl_xor(S, off);

    double cur = val;
    float myw = 0.f; int myidx = 0;
    float psum = 0.f;
    #pragma unroll
    for (int r = 0; r < TOPK; r++) {
      double v = cur; int ii = lane;
      #pragma unroll
      for (int off = 32; off >= 1; off >>= 1) {
        double ov = __shfl_xor(v, off);
        int    oi = __shfl_xor(ii, off);
        if (ov > v || (ov == v && oi < ii)) { v = ov; ii = oi; }
      }
      float pw = __shfl(p, ii);
      psum += pw;
      if (lane == r) { myw = pw; myidx = ii; }
      if (lane == ii) cur = -INFINITY;
    }
    float denom = psum + 1e-20f * S;
    if (lane < TOPK) {
      size_t gt = (size_t)(t0 + t);
      out[gt * TOPK + lane] = myw / denom;
      out[(size_t)n_tokens * TOPK + gt * TOPK + lane] = (float)myidx;
    }
  }
}

extern "C" void kernel_launch(void* const* d_in, const int* in_sizes, int n_in,
                              void* d_out, int out_size, void* d_ws, size_t ws_size,
                              hipStream_t stream)
{
  const float* X  = (const float*)d_in[0];
  const float* Wg = (const float*)d_in[1];
  float* out = (float*)d_out;
  signed char* Wb = (signed char*)d_ws;                 // 1.25 MB limb planes
  double* compT   = (double*)((char*)d_ws + 1310720);   // 512 B comp table
  int n_tokens = in_sizes[0] / H;                        // 16384

  prep_w<<<64, 256, 0, stream>>>(Wg, Wb);
  comp_w<<<64, 64, 0, stream>>>(Wg, compT);
  moe_gate_i8<<<n_tokens / TILE_T, 256, 0, stream>>>(X, Wb, compT, out, n_tokens);
}

// Round 17
// 136.374 us; speedup vs baseline: 1.3430x; 1.0627x over previous
//
#include <hip/hip_runtime.h>
#include <math.h>

typedef float  f32x4  __attribute__((ext_vector_type(4)));
typedef int    i32x4  __attribute__((ext_vector_type(4)));

#define H      4096
#define E      64
#define TOPK   8
#define TILE_T 32
#define CK     256     // k per staged chunk
#define MS     4       // 64-k MFMA steps per chunk
#define NCH    16      // chunks

// W -> 5 balanced i8 limbs of round(w*2^41), B-fragment order for 16x16x64
// (R11-proven): Wb[((m*4+eq)*5+j)*1024 + lane*16 + slot], lane=(kgrp<<4)|(e&15)
__global__ __launch_bounds__(256)
void prep_w(const float* __restrict__ Wg, signed char* __restrict__ Wb)
{
  int n = blockIdx.x * 256 + threadIdx.x;   // 16384 = e(64) x m(64) x kgrp(4)
  int kgrp = n & 3, m = (n >> 2) & 63, e = n >> 8;
  const float* wp = Wg + e * 4096 + m * 64 + kgrp * 16;
  signed char lb[5][16];
  #pragma unroll
  for (int s = 0; s < 16; ++s) {
    long long v = (long long)rint((double)wp[s] * 2199023255552.0); // 2^41
    #pragma unroll
    for (int j = 0; j < 4; ++j) {
      signed char b = (signed char)(v & 0xff);
      lb[j][s] = b;
      v = (v - b) >> 8;
    }
    lb[4][s] = (signed char)v;
  }
  int lanei = (kgrp << 4) | (e & 15);
  int eq = e >> 4;
  #pragma unroll
  for (int j = 0; j < 5; ++j) {
    i32x4 d;
    #pragma unroll
    for (int r = 0; r < 4; ++r)
      d[r] = (lb[j][4*r] & 0xFF) | ((lb[j][4*r+1] & 0xFF) << 8)
           | ((lb[j][4*r+2] & 0xFF) << 16) | ((lb[j][4*r+3] & 0xFF) << 24);
    *(i32x4*)(Wb + (((size_t)(m * 4 + eq) * 5 + j) << 10) + lanei * 16) = d;
  }
}

// comp[e] = C0 * sum_k round(w*2^41), full K (R11-proven).
__global__ __launch_bounds__(64)
void comp_w(const float* __restrict__ Wg, double* __restrict__ compT)
{
  int e = blockIdx.x;
  int lane = threadIdx.x;
  double s = 0.0;
  #pragma unroll 4
  for (int i = 0; i < 64; ++i)
    s += rint((double)Wg[e * 4096 + i * 64 + lane] * 2199023255552.0);
  #pragma unroll
  for (int off = 32; off >= 1; off >>= 1)
    s += __shfl_xor(s, off);
  if (lane == 0) compT[e] = 8421504.0 * s;
}

// R17: PRODUCER/CONSUMER wave specialization. 8 waves: 0-3 consumers (one
// expert-quad each, R14's consume body), 4-7 producers (R14's stage+CONV+
// swizzled write, measured 0 bank conflicts). Phase c: consumers eat buf[c&1]
// while producers convert chunk c+1 into buf[~c&1] -> MFMA and VALU run on
// DIFFERENT waves concurrently (m114). Numerics byte-identical to R8-R16.
__global__ __launch_bounds__(512)
void moe_gate_i8(const float* __restrict__ X, const signed char* __restrict__ Wb,
                 const double* __restrict__ compT, float* __restrict__ out,
                 int n_tokens)
{
  __shared__ char sm[65536];       // 2 x 32KB limb buffers
  double* Ls = (double*)sm;        // aliased epilogue logits [32][64]

  const int tid  = threadIdx.x;
  const int lane = tid & 63;
  const int w    = tid >> 6;     // 0..7
  const int t0   = blockIdx.x * TILE_T;
  const int l15  = lane & 15;
  const int kg   = lane >> 4;

  // ---- probe (lane,reg)->(row,col) readout (R11-proven) ----
  i32x4 z = {0, 0, 0, 0};
  int lab = l15 * 0x01010101;
  i32x4 onev = {0x01010101, 0x01010101, 0x01010101, 0x01010101};
  i32x4 labv = {lab, lab, lab, lab};
  i32x4 pr = __builtin_amdgcn_mfma_i32_16x16x64_i8(labv, onev, z, 0, 0, 0);
  i32x4 pc = __builtin_amdgcn_mfma_i32_16x16x64_i8(onev, labv, z, 0, 0, 0);
  int qrow[4], qcol[4];
  #pragma unroll
  for (int r = 0; r < 4; ++r) { qrow[r] = pr[r] >> 6; qcol[r] = pc[r] >> 6; }

  // consumer state
  i32x4 aA3 = z, aA4 = z, aA5 = z, aA6 = z, aA7 = z;
  i32x4 aB3 = z, aB4 = z, aB5 = z, aB6 = z, aB7 = z;
  const signed char* bpp = Wb + (w & 3) * 5120 + lane * 16;

  // producer state (waves 4-7): tt = (w-4)*8 + lane>>3, ks = lane&7
  const int tt = (w - 4) * 8 + (lane >> 3);
  const int ks = lane & 7;
  const float* xp = X + (size_t)(t0 + (tt & 31)) * H + ks * 32;
  const int swzw = ks << 4;
  char* wb0 = sm + ((ks * 2 + 0) << 11) + (((tt & 31) << 4) ^ swzw);
  char* wb1 = sm + ((ks * 2 + 1) << 11) + (((tt & 31) << 4) ^ swzw);

  // CONV: 4 x f32x4 -> 4 limb-plane words (R9-proven perm tree)
  #define CONV(xr, hf, W0, W1, W2, W3)                                        \
  {                                                                           \
    unsigned w32[16];                                                         \
    _Pragma("unroll")                                                         \
    for (int r = 0; r < 4; ++r) {                                             \
      f32x4 xv = xr[(hf) * 4 + r];                                            \
      _Pragma("unroll")                                                       \
      for (int jj = 0; jj < 4; ++jj)                                          \
        w32[r*4+jj] = ((unsigned)(int)(xv[jj] * 268435456.0f)) ^ 0x00808080u; \
    }                                                                         \
    _Pragma("unroll")                                                         \
    for (int r = 0; r < 4; ++r) {                                             \
      unsigned u0 = w32[4*r], u1 = w32[4*r+1], u2 = w32[4*r+2], u3 = w32[4*r+3];\
      unsigned p01, p23;                                                      \
      p01 = __builtin_amdgcn_perm(u1, u0, 0x04000400u);                       \
      p23 = __builtin_amdgcn_perm(u3, u2, 0x04000400u);                       \
      W0[r] = (int)__builtin_amdgcn_perm(p23, p01, 0x05040100u);              \
      p01 = __builtin_amdgcn_perm(u1, u0, 0x05010501u);                       \
      p23 = __builtin_amdgcn_perm(u3, u2, 0x05010501u);                       \
      W1[r] = (int)__builtin_amdgcn_perm(p23, p01, 0x05040100u);              \
      p01 = __builtin_amdgcn_perm(u1, u0, 0x06020602u);                       \
      p23 = __builtin_amdgcn_perm(u3, u2, 0x06020602u);                       \
      W2[r] = (int)__builtin_amdgcn_perm(p23, p01, 0x05040100u);              \
      p01 = __builtin_amdgcn_perm(u1, u0, 0x07030703u);                       \
      p23 = __builtin_amdgcn_perm(u3, u2, 0x07030703u);                       \
      W3[r] = (int)__builtin_amdgcn_perm(p23, p01, 0x05040100u);              \
    }                                                                         \
  }

  #define PRODUCE(c_, wbuf_)                                                  \
  {                                                                           \
    f32x4 xr[8];                                                              \
    _Pragma("unroll")                                                         \
    for (int q = 0; q < 8; ++q)                                               \
      xr[q] = *(const f32x4*)(xp + (size_t)(c_) * CK + 4 * q);                \
    i32x4 U0, U1, U2, U3, V0, V1, V2, V3;                                     \
    CONV(xr, 0, U0, U1, U2, U3);                                              \
    CONV(xr, 1, V0, V1, V2, V3);                                              \
    char* b0_ = wb0 + ((wbuf_) << 15);                                        \
    char* b1_ = wb1 + ((wbuf_) << 15);                                        \
    *(i32x4*)(b0_ + 0x000) = U0;                                              \
    *(i32x4*)(b0_ + 0x200) = U1;                                              \
    *(i32x4*)(b0_ + 0x400) = U2;                                              \
    *(i32x4*)(b0_ + 0x600) = U3;                                              \
    *(i32x4*)(b1_ + 0x000) = V0;                                              \
    *(i32x4*)(b1_ + 0x200) = V1;                                              \
    *(i32x4*)(b1_ + 0x400) = V2;                                              \
    *(i32x4*)(b1_ + 0x600) = V3;                                              \
  }

  // ---- prologue: producers fill buf0 ----
  if (w >= 4) PRODUCE(0, 0);
  __syncthreads();

  for (int c = 0; c < NCH; ++c) {
    const int cur = c & 1;
    if (w < 4) {
      // consumers: eat buf[cur] (R14-proven body; B loads hoisted per step)
      const char* base = sm + (cur << 15);
      #pragma unroll
      for (int m = 0; m < MS; ++m) {
        const int kq   = 4 * m + kg;
        const int swzr = ((kq >> 1) & 7) << 4;
        const char* abase = base + (kq << 11) + (((l15 << 4) ^ swzr));
        i32x4 b0 = *(const i32x4*)(bpp);
        i32x4 b1 = *(const i32x4*)(bpp + 1024);
        i32x4 b2 = *(const i32x4*)(bpp + 2048);
        i32x4 b3 = *(const i32x4*)(bpp + 3072);
        i32x4 b4 = *(const i32x4*)(bpp + 4096);
        bpp += 20480;
        i32x4 xA0 = *(const i32x4*)(abase + 0x000);
        i32x4 xA1 = *(const i32x4*)(abase + 0x200);
        i32x4 xA2 = *(const i32x4*)(abase + 0x400);
        i32x4 xA3 = *(const i32x4*)(abase + 0x600);
        i32x4 xB0 = *(const i32x4*)(abase + 0x100);
        i32x4 xB1 = *(const i32x4*)(abase + 0x300);
        i32x4 xB2 = *(const i32x4*)(abase + 0x500);
        i32x4 xB3 = *(const i32x4*)(abase + 0x700);
        aA3 = __builtin_amdgcn_mfma_i32_16x16x64_i8(xA0, b3, aA3, 0, 0, 0);
        aB3 = __builtin_amdgcn_mfma_i32_16x16x64_i8(xB0, b3, aB3, 0, 0, 0);
        aA4 = __builtin_amdgcn_mfma_i32_16x16x64_i8(xA0, b4, aA4, 0, 0, 0);
        aB4 = __builtin_amdgcn_mfma_i32_16x16x64_i8(xB0, b4, aB4, 0, 0, 0);
        aA5 = __builtin_amdgcn_mfma_i32_16x16x64_i8(xA1, b4, aA5, 0, 0, 0);
        aB5 = __builtin_amdgcn_mfma_i32_16x16x64_i8(xB1, b4, aB5, 0, 0, 0);
        aA6 = __builtin_amdgcn_mfma_i32_16x16x64_i8(xA2, b4, aA6, 0, 0, 0);
        aB6 = __builtin_amdgcn_mfma_i32_16x16x64_i8(xB2, b4, aB6, 0, 0, 0);
        aA7 = __builtin_amdgcn_mfma_i32_16x16x64_i8(xA3, b4, aA7, 0, 0, 0);
        aB7 = __builtin_amdgcn_mfma_i32_16x16x64_i8(xB3, b4, aB7, 0, 0, 0);
        aA3 = __builtin_amdgcn_mfma_i32_16x16x64_i8(xA1, b2, aA3, 0, 0, 0);
        aB3 = __builtin_amdgcn_mfma_i32_16x16x64_i8(xB1, b2, aB3, 0, 0, 0);
        aA4 = __builtin_amdgcn_mfma_i32_16x16x64_i8(xA1, b3, aA4, 0, 0, 0);
        aB4 = __builtin_amdgcn_mfma_i32_16x16x64_i8(xB1, b3, aB4, 0, 0, 0);
        aA5 = __builtin_amdgcn_mfma_i32_16x16x64_i8(xA2, b3, aA5, 0, 0, 0);
        aB5 = __builtin_amdgcn_mfma_i32_16x16x64_i8(xB2, b3, aB5, 0, 0, 0);
        aA6 = __builtin_amdgcn_mfma_i32_16x16x64_i8(xA3, b3, aA6, 0, 0, 0);
        aB6 = __builtin_amdgcn_mfma_i32_16x16x64_i8(xB3, b3, aB6, 0, 0, 0);
        aA3 = __builtin_amdgcn_mfma_i32_16x16x64_i8(xA2, b1, aA3, 0, 0, 0);
        aB3 = __builtin_amdgcn_mfma_i32_16x16x64_i8(xB2, b1, aB3, 0, 0, 0);
        aA4 = __builtin_amdgcn_mfma_i32_16x16x64_i8(xA2, b2, aA4, 0, 0, 0);
        aB4 = __builtin_amdgcn_mfma_i32_16x16x64_i8(xB2, b2, aB4, 0, 0, 0);
        aA5 = __builtin_amdgcn_mfma_i32_16x16x64_i8(xA3, b2, aA5, 0, 0, 0);
        aB5 = __builtin_amdgcn_mfma_i32_16x16x64_i8(xB3, b2, aB5, 0, 0, 0);
        aA3 = __builtin_amdgcn_mfma_i32_16x16x64_i8(xA3, b0, aA3, 0, 0, 0);
        aB3 = __builtin_amdgcn_mfma_i32_16x16x64_i8(xB3, b0, aB3, 0, 0, 0);
        aA4 = __builtin_amdgcn_mfma_i32_16x16x64_i8(xA3, b1, aA4, 0, 0, 0);
        aB4 = __builtin_amdgcn_mfma_i32_16x16x64_i8(xB3, b1, aB4, 0, 0, 0);
      }
    } else {
      // producers: convert chunk c+1 into the buffer consumers aren't reading
      if (c < NCH - 1) PRODUCE(c + 1, cur ^ 1);
    }
    __syncthreads();
  }
  #undef PRODUCE
  #undef CONV

  // ---- f64 combine (consumers own accs; sm staging dead -> Ls aliases) ----
  if (w < 4) {
    #pragma unroll
    for (int r = 0; r < 4; ++r) {
      int ex = (w & 3) * 16 + qcol[r];
      double pA = (16777216.0          * (double)aA3[r]
                 + 4294967296.0        * (double)aA4[r]
                 + 1099511627776.0     * (double)aA5[r]
                 + 281474976710656.0   * (double)aA6[r]
                 + 72057594037927936.0 * (double)aA7[r]
                 + compT[ex]) * 1.6940658945086007e-21;
      double pB = (16777216.0          * (double)aB3[r]
                 + 4294967296.0        * (double)aB4[r]
                 + 1099511627776.0     * (double)aB5[r]
                 + 281474976710656.0   * (double)aB6[r]
                 + 72057594037927936.0 * (double)aB7[r]
                 + compT[ex]) * 1.6940658945086007e-21;
      Ls[qrow[r] * E + ex]        = pA;
      Ls[(16 + qrow[r]) * E + ex] = pB;
    }
  }
  __syncthreads();

  // ---- softmax + top-8 on f64 logits: 8 waves x 4 tokens ----
  for (int tt2 = 0; tt2 < 4; tt2++) {
    int t = w * 4 + tt2;
    double val = Ls[t * E + lane];

    double mx = val;
    #pragma unroll
    for (int off = 32; off >= 1; off >>= 1)
      mx = fmax(mx, __shfl_xor(mx, off));

    float p = expf((float)(val - mx));
    float S = p;
    #pragma unroll
    for (int off = 32; off >= 1; off >>= 1)
      S += __shfl_xor(S, off);

    double cur = val;
    float myw = 0.f; int myidx = 0;
    float psum = 0.f;
    #pragma unroll
    for (int r = 0; r < TOPK; r++) {
      double v = cur; int ii = lane;
      #pragma unroll
      for (int off = 32; off >= 1; off >>= 1) {
        double ov = __shfl_xor(v, off);
        int    oi = __shfl_xor(ii, off);
        if (ov > v || (ov == v && oi < ii)) { v = ov; ii = oi; }
      }
      float pw = __shfl(p, ii);
      psum += pw;
      if (lane == r) { myw = pw; myidx = ii; }
      if (lane == ii) cur = -INFINITY;
    }
    float denom = psum + 1e-20f * S;
    if (lane < TOPK) {
      size_t gt = (size_t)(t0 + t);
      out[gt * TOPK + lane] = myw / denom;
      out[(size_t)n_tokens * TOPK + gt * TOPK + lane] = (float)myidx;
    }
  }
}

extern "C" void kernel_launch(void* const* d_in, const int* in_sizes, int n_in,
                              void* d_out, int out_size, void* d_ws, size_t ws_size,
                              hipStream_t stream)
{
  const float* X  = (const float*)d_in[0];
  const float* Wg = (const float*)d_in[1];
  float* out = (float*)d_out;
  signed char* Wb = (signed char*)d_ws;                 // 1.25 MB limb planes
  double* compT   = (double*)((char*)d_ws + 1310720);   // 512 B comp table
  int n_tokens = in_sizes[0] / H;                        // 16384

  prep_w<<<64, 256, 0, stream>>>(Wg, Wb);
  comp_w<<<64, 64, 0, stream>>>(Wg, compT);
  moe_gate_i8<<<n_tokens / TILE_T, 512, 0, stream>>>(X, Wb, compT, out, n_tokens);
}